// Round 21
// baseline (91.021 us; speedup 1.0000x reference)
//
#include <hip/hip_runtime.h>

#define MM 4096
#define NN 4096
#define KK 4096
#define BM 256
#define BN 256
#define BK 64
#define NT (KK / BK)
#define QSCALE 24.0f

typedef int           i32x4 __attribute__((ext_vector_type(4)));

#define MFMAI8(a, b, c) __builtin_amdgcn_mfma_i32_16x16x64_i8((a), (b), (c), 0, 0, 0)
#define SB0() __builtin_amdgcn_sched_barrier(0)
#define LGKM(n) asm volatile("s_waitcnt lgkmcnt(" #n ")" ::: "memory")
#define VMC(n)  asm volatile("s_waitcnt vmcnt(" #n ")" ::: "memory")

// ---------- helpers ----------

__device__ __forceinline__ void gload16(const void* g, void* l) {
  __builtin_amdgcn_global_load_lds(
      (const __attribute__((address_space(1))) void*)g,
      (__attribute__((address_space(3))) void*)l, 16, 0, 0);
}
__device__ __forceinline__ void gload4(const void* g, void* l) {
  __builtin_amdgcn_global_load_lds(
      (const __attribute__((address_space(1))) void*)g,
      (__attribute__((address_space(3))) void*)l, 4, 0, 0);
}

__device__ __forceinline__ int q8(float v) {
  int q = (int)rintf(v * QSCALE);
  q = q > 127 ? 127 : q;
  q = q < -127 ? -127 : q;
  return q & 255;
}

// ---------- kernel 1: fused preprocessing ----------
// blocks [0,2048): 2:4 mask + binarize -> BIT-PACKED wp (M x K / 8 bytes),
//   GEMM-ready layout: chunk(bmi,t)=2048B; entry16B(wm,llo,lhi)=u16[m];
//   u16 bit j = keep(row=bmi*256+wm*128+m*16+llo, k=t*64+lhi*16+j).
// blocks [2048,6144): x (K x N f32) -> xT i8 (N x K), 64x64 transpose,
//   xq = clamp(rint(24*x),-127,127).

__global__ __launch_bounds__(256) void kpre(const float* __restrict__ w,
                                            const float* __restrict__ x,
                                            unsigned char* __restrict__ wp,
                                            signed char* __restrict__ xt) {
  __shared__ float tile[64][65];
  __shared__ unsigned char pknib[128][16];
  const int t = threadIdx.x;

  if (blockIdx.x < 2048) {
    // ---- quant+pack path: block owns (bmi, k-tile tt, wm half) ----
    const int qb  = blockIdx.x;
    const int bmi = qb >> 7;
    const int tt  = (qb >> 1) & 63;
    const int wmq = qb & 1;
    const size_t rowbase = (size_t)bmi * 256 + (size_t)wmq * 128;
    const int kbase = tt * 64;

    // phase 1: 128 rows x 64 k -> keep-nibbles (one group of 4 per thread-pass)
    const int g  = t & 15;          // k-group (4 weights)
    const int r0 = t >> 4;
#pragma unroll
    for (int p = 0; p < 8; p++) {
      int rloc = r0 + p * 16;
      float4 v = *(const float4*)(w + (rowbase + rloc) * (size_t)KK + kbase + g * 4);
      float a0 = fabsf(v.x), a1 = fabsf(v.y), a2 = fabsf(v.z), a3 = fabsf(v.w);
      int bits = 0, rank;
      rank = (a1 > a0) + (a2 > a0) + (a3 > a0);
      if (rank < 2 && v.x > 0.0f) bits |= 1;
      rank = (a0 >= a1) + (a2 > a1) + (a3 > a1);
      if (rank < 2 && v.y > 0.0f) bits |= 2;
      rank = (a0 >= a2) + (a1 >= a2) + (a3 > a2);
      if (rank < 2 && v.z > 0.0f) bits |= 4;
      rank = (a0 >= a3) + (a1 >= a3) + (a2 >= a3);
      if (rank < 2 && v.w > 0.0f) bits |= 8;
      pknib[rloc][g] = (unsigned char)bits;
    }
    __syncthreads();

    // phase 2: assemble u16 pairs, coalesced 1KB write
    const int e    = t >> 2;        // entry in this wm-half: llo*4+lhi
    const int lloq = e >> 2;
    const int lhiq = e & 3;
    const int m0   = (t & 3) * 2;
    unsigned out = 0;
#pragma unroll
    for (int hh = 0; hh < 2; hh++) {
      int row = (m0 + hh) * 16 + lloq;
      unsigned raw = *(const unsigned*)&pknib[row][lhiq * 4];
      unsigned nn = raw & 0x0F0F0F0Fu;
      nn = (nn | (nn >> 4)) & 0x00FF00FFu;
      nn = (nn | (nn >> 8)) & 0x0000FFFFu;
      out |= nn << (hh * 16);
    }
    *(unsigned*)(wp + ((((size_t)(bmi * 64 + tt)) * 2 + wmq) << 10) + t * 4) = out;
    return;
  }

  // ---- transpose + quantize path ----
  int bid2 = blockIdx.x - 2048;
  int bn = bid2 & 63;
  int bk = bid2 >> 6;
  int tc = (t & 15) << 2;
  int tr = t >> 4;
  const float* src = x + (size_t)(bk * 64 + tr) * NN + bn * 64 + tc;
#pragma unroll
  for (int i = 0; i < 4; i++) {
    float4 v = *(const float4*)(src + (size_t)i * 16 * NN);
    int r = tr + i * 16;
    tile[r][tc + 0] = v.x; tile[r][tc + 1] = v.y;
    tile[r][tc + 2] = v.z; tile[r][tc + 3] = v.w;
  }
  __syncthreads();
#pragma unroll
  for (int i = 0; i < 4; i++) {
    int n = tr + i * 16;
    unsigned int q = (unsigned)q8(tile[tc + 0][n])
                   | ((unsigned)q8(tile[tc + 1][n]) << 8)
                   | ((unsigned)q8(tile[tc + 2][n]) << 16)
                   | ((unsigned)q8(tile[tc + 3][n]) << 24);
    *(unsigned int*)(xt + (size_t)(bn * 64 + n) * KK + bk * 64 + tc) = q;
  }
}

// ---------- kernel 2: 256x256 i8 GEMM, bit-packed A, tri-buffer + VMC(3) ---
// Per wave per tile: 1 ds_read_b128 (ALL packed A) + 4 B reads + 32 MFMA +
// ~96 VALU expansion ((nib*0x204081)&0x01010101 per dword). Ledger (in-order
// DS retire): enter with out=5 {PA,BF of t}; LGKM(0) -> expand afl -> Q-lo ->
// stage(t+2: 3 gloads) -> VMC(3) [stage(t+1) landed, issued full tile ago] ->
// barrier [collective certify buf(t+1); also WAR anchor: barrier(t-1) after
// each wave's LGKM(0)(t-1) = buf(t-1) readers done before stage at t+... ] ->
// read 5 of t+1 (drain under expansion+Q-hi) -> expand afh -> Q-hi.

__global__ __launch_bounds__(512, 2) void kgemm(const unsigned char* __restrict__ WP,
                                                const signed char* __restrict__ B,
                                                float* __restrict__ C) {
  __shared__ __align__(16) char lds[8192 + 49152];  // PA 3x2048 @0 | B 3x16384 @8192

  const int tid  = threadIdx.x;
  const int bid  = blockIdx.x;
  const int xcd  = bid & 7;
  const int j    = bid >> 3;
  const int bmi  = (xcd >> 1) * 4 + (j >> 3);
  const int bni  = (xcd & 1) * 8 + (j & 7);
  const int lane = tid & 63;
  const int wave = tid >> 6;
  const int wm   = wave >> 2;
  const int wn   = wave & 3;
  const int llo  = lane & 15;
  const int lhi  = lane >> 4;

  // B staging source (inverse-swizzled, r18-verified)
  const int L   = tid >> 3;
  const int pgs = tid & 7;
  const int lg  = pgs ^ (L & 7);
  const int rl  = (L << 1) | (lg >> 2);
  const int gq  = lg & 3;
  const signed char* gb = B + (size_t)(bni * BN + rl) * KK + gq * 16;

  // B fragment read offset (r18-verified, 0-conflict)
  const int pg   = (((llo & 1) << 2) + lhi) ^ ((llo >> 1) & 7);
  const int boff = (wn >> 1) * 8192 + ((wn & 1) * 32 + (llo >> 1)) * 128 + pg * 16;

  // packed-A fragment read offset (linear 16B/lane, conflict-free)
  const int paoff = (wm * 64 + llo * 4 + lhi) * 16;

  i32x4 acc[8][4] = {};
  i32x4 paA, paB;
  i32x4 bfA[4], bfB[4];
  i32x4 af[4];

  auto stage = [&](int buf, int t) {   // 1 PA-gload + 2 B-gloads per thread
    gload4(WP + (((size_t)(bmi * 64 + t)) << 11) + tid * 4,
           lds + buf * 2048 + tid * 4);
#pragma unroll
    for (int c = 0; c < 2; c++)
      gload16(gb + (size_t)c * 128 * KK + t * 64,
              lds + 8192 + buf * 16384 + c * 8192 + tid * 16);
  };
  auto readPA = [&](i32x4& pa, int buf) {
    pa = *(const i32x4*)(lds + buf * 2048 + paoff);
  };
  auto readBF = [&](i32x4 (&bf)[4], int buf) {
#pragma unroll
    for (int n = 0; n < 4; n++)
      bf[n] = *(const i32x4*)(lds + 8192 + buf * 16384 + boff + n * 1024);
  };
  auto expand = [&](const i32x4& pa, int half) {  // 4 frags -> af[0..3]
#pragma unroll
    for (int m = 0; m < 4; m++) {
      const int mm = half * 4 + m;
      const unsigned w32 = (unsigned)pa[mm >> 1];
      const int base = (mm & 1) * 16;
#pragma unroll
      for (int d = 0; d < 4; d++) {
        unsigned nib = (w32 >> (base + 4 * d)) & 15u;
        af[m][d] = (int)((nib * 0x00204081u) & 0x01010101u);
      }
    }
  };

  auto body = [&](i32x4& paC, i32x4 (&bfC)[4], i32x4& paN, i32x4 (&bfN)[4], int t) {
    const int b2 = (t + 2) % 3;
    const int b1 = (t + 1) % 3;
    const int tn = (t + 2) & (NT - 1);   // wraps on last iters (dead loads)

    LGKM(0); SB0();            // paC,bfC landed (issued post-barrier last tile)

    expand(paC, 0);            // afl
    __builtin_amdgcn_s_setprio(1);
#pragma unroll
    for (int m = 0; m < 4; m++)
#pragma unroll
      for (int n = 0; n < 4; n++)
        acc[m][n] = MFMAI8(af[m], bfC[n], acc[m][n]);
    __builtin_amdgcn_s_setprio(0);
    SB0();

    stage(b2, tn); SB0();      // buf(t-1): readers done via LGKM(0)(t-1)+barrier(t-1)
    VMC(3); SB0();             // stage(t+1) landed (issued a full tile ago)
    __builtin_amdgcn_s_barrier(); SB0();

    readPA(paN, b1); readBF(bfN, b1); SB0();   // out=5, drain under expand+Q-hi

    expand(paC, 1);            // afh
    __builtin_amdgcn_s_setprio(1);
#pragma unroll
    for (int m = 0; m < 4; m++)
#pragma unroll
      for (int n = 0; n < 4; n++)
        acc[4 + m][n] = MFMAI8(af[m], bfC[n], acc[4 + m][n]);
    __builtin_amdgcn_s_setprio(0);
    SB0();
  };

  // prologue: tiles 0,1 -> bufs 0,1; certify tile 0; issue its 5 reads
  stage(0, 0);
  stage(1, 1);
  VMC(3); SB0();               // tile 0 landed; tile 1 flying
  __builtin_amdgcn_s_barrier(); SB0();
  readPA(paA, 0); readBF(bfA, 0); SB0();

  for (int it = 0; it < NT / 2; ++it) {
    body(paA, bfA, paB, bfB, 2 * it);
    body(paB, bfB, paA, bfA, 2 * it + 1);
  }

  // ---- epilogue: D layout col = lane&15, row = (lane>>4)*4 + reg; scale 1/24
  const int crow0 = bmi * BM + wm * 128 + lhi * 4;
  const int ccol0 = bni * BN + wn * 64 + llo;
  const float ds = 1.0f / QSCALE;
#pragma unroll
  for (int m = 0; m < 8; m++)
#pragma unroll
    for (int n = 0; n < 4; n++) {
      float* cp = C + (size_t)(crow0 + m * 16) * NN + ccol0 + n * 16;
#pragma unroll
      for (int v = 0; v < 4; v++) cp[(size_t)v * NN] = (float)acc[m][n][v] * ds;
    }
}

// ---------- fallback: fused fp32 tiled GEMM (workspace too small) ----------

__device__ __forceinline__ float binq_elem(const float g[4], int j) {
  float aj = fabsf(g[j]);
  int rank = 0;
#pragma unroll
  for (int k = 0; k < 4; k++) {
    if (k == j) continue;
    float ak = fabsf(g[k]);
    rank += (ak > aj || (ak == aj && k < j)) ? 1 : 0;
  }
  return (rank < 2 && g[j] > 0.0f) ? 1.0f : 0.0f;
}

__global__ __launch_bounds__(256) void kfallback(const float* __restrict__ x,
                                                 const float* __restrict__ w,
                                                 float* __restrict__ c) {
  __shared__ float sA[16][17];
  __shared__ float sB[16][17];
  int tx = threadIdx.x, ty = threadIdx.y;
  int row = blockIdx.y * 16 + ty;
  int col = blockIdx.x * 16 + tx;
  float acc = 0.0f;
  for (int k0 = 0; k0 < KK; k0 += 16) {
    int k = k0 + tx;
    const float* g = &w[(size_t)row * KK + (k & ~3)];
    float gv[4] = {g[0], g[1], g[2], g[3]};
    sA[ty][tx] = binq_elem(gv, k & 3);
    sB[ty][tx] = x[(size_t)(k0 + ty) * NN + col];
    __syncthreads();
#pragma unroll
    for (int kk = 0; kk < 16; kk++) acc += sA[ty][kk] * sB[kk][tx];
    __syncthreads();
  }
  c[(size_t)row * NN + col] = acc;
}

// ---------- launcher ----------

extern "C" void kernel_launch(void* const* d_in, const int* in_sizes, int n_in,
                              void* d_out, int out_size, void* d_ws, size_t ws_size,
                              hipStream_t stream) {
  const float* x = (const float*)d_in[0];
  const float* w = (const float*)d_in[1];
  float* out = (float*)d_out;

  const size_t need = (size_t)MM * KK / 8 + (size_t)NN * KK;  // 2MB + 16.7MB
  if (ws_size < need) {
    dim3 blk(16, 16);
    dim3 grd(NN / 16, MM / 16);
    kfallback<<<grd, blk, 0, stream>>>(x, w, out);
    return;
  }

  unsigned char* wp = (unsigned char*)d_ws;
  signed char*   xt = (signed char*)(wp + (size_t)MM * KK / 8);

  kpre<<<6144, 256, 0, stream>>>(w, x, wp, xt);
  kgemm<<<dim3((MM / BM) * (NN / BN)), 512, 0, stream>>>(wp, xt, out);
}